// Round 11
// baseline (128.372 us; speedup 1.0000x reference)
//
#include <hip/hip_runtime.h>
#include <stdint.h>

#define NT 2048     // tokens
#define TD 1024     // token dim
#define NH 16       // heads
static constexpr float SCL = 0.18033688011112042f;  // beta*log2(e), applied in exp2

typedef __attribute__((ext_vector_type(8))) short bf16x8;
typedef __attribute__((ext_vector_type(4))) float f32x4;
typedef __attribute__((ext_vector_type(16))) float f32x16;
typedef __attribute__((address_space(3))) uint32_t lds_u32;
typedef __attribute__((address_space(1))) uint32_t glb_u32;

__device__ __forceinline__ float bf2f(unsigned short u){
  union { uint32_t u32; float f; } v; v.u32 = ((uint32_t)u) << 16; return v.f;
}
__device__ __forceinline__ unsigned short f2bf(float f){
  union { float f; uint32_t u; } v; v.f = f;
  uint32_t r = v.u + 0x7fffu + ((v.u >> 16) & 1u);   // RNE
  return (unsigned short)(r >> 16);
}
// 128B-row tile (8x16B slots), phys slot = kc ^ (row&7)
__device__ __forceinline__ bf16x8 ld8(const unsigned short* base, int row, int kc){
  return *(const bf16x8*)((const char*)base + row*128 + ((kc ^ (row & 7)) << 4));
}
template<int N> __device__ __forceinline__ void wait_vm_lgkm0(){
  if constexpr (N == 0)      asm volatile("s_waitcnt vmcnt(0) lgkmcnt(0)" ::: "memory");
  else if constexpr (N == 4) asm volatile("s_waitcnt vmcnt(4) lgkmcnt(0)" ::: "memory");
  else if constexpr (N == 6) asm volatile("s_waitcnt vmcnt(6) lgkmcnt(0)" ::: "memory");
  __builtin_amdgcn_sched_barrier(0);
}
__device__ __forceinline__ void lgkm0_fence(){
  asm volatile("s_waitcnt lgkmcnt(0)" ::: "memory");
  __builtin_amdgcn_sched_barrier(0);
}

// ------------------------------------------------------------------
// prep: gbf = bf16(g); wkq = bf16([Wk;Wq]) rows hz2 x 1024;
//       twqk[d][j] = j<1024 ? Wq[j][d] : Wk[j-1024][d]  (bf16, 1024x2048)
// ------------------------------------------------------------------
__global__ __launch_bounds__(256) void prep_kernel(
    const float* __restrict__ g, const float* __restrict__ Wk, const float* __restrict__ Wq,
    unsigned short* __restrict__ gbf, unsigned short* __restrict__ wkq,
    unsigned short* __restrict__ twqk)
{
  int b = blockIdx.x;
  if (b < 1024) {
    int base = b * 2048 + threadIdx.x;
    #pragma unroll
    for (int i = 0; i < 8; i++) { int idx = base + i * 256; gbf[idx] = f2bf(g[idx]); }
  } else if (b < 2048) {
    int base = (b - 1024) * 2048 + threadIdx.x;
    #pragma unroll
    for (int i = 0; i < 8; i++) {
      int idx = base + i * 256;
      float v = (idx < (1 << 20)) ? Wk[idx] : Wq[idx - (1 << 20)];
      wkq[idx] = f2bf(v);
    }
  } else {
    int t = b - 2048;                  // 32 d-tiles x 64 j-tiles
    int dt = t & 31, jt = t >> 5;
    __shared__ float tile[32][33];
    int tx = threadIdx.x & 31, ty = threadIdx.x >> 5;
    int j0 = jt * 32, d0 = dt * 32;
    const float* src = (j0 < 1024) ? Wq : Wk;
    int jb = (j0 < 1024) ? j0 : (j0 - 1024);
    #pragma unroll
    for (int rr = 0; rr < 4; rr++)
      tile[ty + rr * 8][tx] = src[(size_t)(jb + ty + rr * 8) * 1024 + d0 + tx];
    __syncthreads();
    #pragma unroll
    for (int rr = 0; rr < 4; rr++)
      twqk[(size_t)(d0 + ty + rr * 8) * 2048 + j0 + tx] = f2bf(tile[tx][ty + rr * 8]);
  }
}

// ------------------------------------------------------------------
// transp: TKQ[j][m] = CKQ[m][j]  (2048x2048 bf16, coalesced LDS transpose)
// ------------------------------------------------------------------
__global__ __launch_bounds__(256) void transp_kernel(const unsigned short* __restrict__ in,
                                                     unsigned short* __restrict__ out)
{
  int t = blockIdx.x; int jt = t & 63, mt = t >> 6;
  __shared__ unsigned short tile[32][33];
  int tx = threadIdx.x & 31, ty = threadIdx.x >> 5;
  int m0 = mt * 32, j0 = jt * 32;
  #pragma unroll
  for (int rr = 0; rr < 4; rr++)
    tile[ty + rr * 8][tx] = in[(size_t)(m0 + ty + rr * 8) * 2048 + j0 + tx];
  __syncthreads();
  #pragma unroll
  for (int rr = 0; rr < 4; rr++)
    out[(size_t)(j0 + ty + rr * 8) * 2048 + m0 + tx] = tile[tx][ty + rr * 8];
}

// ------------------------------------------------------------------
// qst: QsT[r][q] = TKQ[1024+r][q] / L[r>>6][q]
// ------------------------------------------------------------------
__global__ __launch_bounds__(256) void qst_kernel(const unsigned short* __restrict__ tkq,
                                                  const float* __restrict__ L,
                                                  unsigned short* __restrict__ qst)
{
  int r = blockIdx.x;
  int h = r >> 6;
  const unsigned short* src = tkq + (size_t)(1024 + r) * 2048;
  unsigned short* dst = qst + (size_t)r * 2048;
  const float* Lh = L + (size_t)h * NT;
  for (int q = threadIdx.x; q < NT; q += 256)
    dst[q] = f2bf(bf2f(src[q]) / Lh[q]);
}

// ------------------------------------------------------------------
// btg2: C = A[M x K] * BT[N x K]^T, bf16, BK=64, triple-buffered counted vmcnt.
// EPI 0: C0 = bf16 C (ld 2048), coalesced rows only                  [KQ]
// EPI 4: C0 f32 [r][1024] = -acc                                     [out]
// ------------------------------------------------------------------
template<int TM, int TN, int EPI, int WPE>
__global__ __launch_bounds__(256, WPE) void btg2_kernel(
    const unsigned short* __restrict__ A, int lda,
    const unsigned short* __restrict__ BT, int ldb,
    int Kdim, void* C0)
{
  constexpr int WM = TM / 2, WN = TN / 2, FM = WM / 16, FN = WN / 16;
  constexpr int AC = TM / 32, BC = TN / 32, LOADS = AC + BC;
  __shared__ __align__(16) unsigned short As[3][TM * 64];
  __shared__ __align__(16) unsigned short Bs[3][TN * 64];
  int tid = threadIdx.x, lane = tid & 63, wave = tid >> 6;
  int wr = wave >> 1, wc = wave & 1, lrow = lane & 15, g = lane >> 4;
  int bm = blockIdx.x * TM, bn = blockIdx.y * TN;

  auto stage = [&](unsigned short* bufA, unsigned short* bufB, int kk) {
    #pragma unroll
    for (int i = 0; i < AC; i++) {
      int c = i * 256 + tid, row = c >> 3, sl = ((c & 7) ^ (row & 7)) << 3;
      __builtin_amdgcn_global_load_lds((glb_u32*)(A + (size_t)(bm + row) * lda + kk + sl),
          (lds_u32*)((char*)bufA + i * 4096 + wave * 1024), 16, 0, 0);
    }
    #pragma unroll
    for (int i = 0; i < BC; i++) {
      int c = i * 256 + tid, row = c >> 3, sl = ((c & 7) ^ (row & 7)) << 3;
      __builtin_amdgcn_global_load_lds((glb_u32*)(BT + (size_t)(bn + row) * ldb + kk + sl),
          (lds_u32*)((char*)bufB + i * 4096 + wave * 1024), 16, 0, 0);
    }
  };

  f32x4 acc[FM][FN] = {};
  int nt = Kdim >> 6;
  stage(As[0], Bs[0], 0);
  stage(As[1], Bs[1], 64);
  wait_vm_lgkm0<LOADS>();          // tile0 landed; tile1 still in flight
  __builtin_amdgcn_s_barrier();
  int bc = 0;
  for (int t = 0; t < nt; t++) {
    int bp = bc + 2; if (bp >= 3) bp -= 3;
    if (t + 2 < nt) stage(As[bp], Bs[bp], (t + 2) * 64);
    const unsigned short* Ac = As[bc];
    const unsigned short* Bc = Bs[bc];
    #pragma unroll
    for (int k2 = 0; k2 < 2; k2++) {
      bf16x8 a_[FM], b_[FN];
      #pragma unroll
      for (int m = 0; m < FM; m++) a_[m] = ld8(Ac, wr * WM + m * 16 + lrow, k2 * 4 + g);
      #pragma unroll
      for (int n = 0; n < FN; n++) b_[n] = ld8(Bc, wc * WN + n * 16 + lrow, k2 * 4 + g);
      #pragma unroll
      for (int m = 0; m < FM; m++)
        #pragma unroll
        for (int n = 0; n < FN; n++)
          acc[m][n] = __builtin_amdgcn_mfma_f32_16x16x32_bf16(a_[m], b_[n], acc[m][n], 0, 0, 0);
    }
    if (t + 2 < nt) wait_vm_lgkm0<LOADS>(); else wait_vm_lgkm0<0>();
    __builtin_amdgcn_s_barrier();
    bc = (bc == 2) ? 0 : bc + 1;
  }
  #pragma unroll
  for (int m = 0; m < FM; m++) {
    int rb = bm + wr * WM + m * 16 + 4 * g;
    #pragma unroll
    for (int n = 0; n < FN; n++) {
      int cc = bn + wc * WN + n * 16 + lrow;
      f32x4 v = acc[m][n];
      if constexpr (EPI == 0) {
        unsigned short* Cp = (unsigned short*)C0;
        #pragma unroll
        for (int j = 0; j < 4; j++) Cp[(size_t)(rb + j) * 2048 + cc] = f2bf(v[j]);
      } else {
        float* Cf = (float*)C0;
        #pragma unroll
        for (int j = 0; j < 4; j++) Cf[(size_t)(rb + j) * 1024 + cc] = -v[j];
      }
    }
  }
}

// ------------------------------------------------------------------
// fused flash kernel v11 = round-10 dataflow, re-scheduled as a 3-phase
// m201-style interleave. All address math / sigma / fragment formulas are
// byte-identical to round 10 (verified); ONLY barrier/phase structure changed:
//   P0: {ds_read 4 a-frags || stageAin(t+2)} bar lgkm0 [8 S-MFMA] bar
//   P1: {ds_read 4 pb(zb0) || stageAux(t+2); exp2+cvt} bar lgkm0 [4 PV-MFMA] bar
//   P2: {ds_read 4 pb(zb1)} bar lgkm0 [4 PV-MFMA] vmcnt(4) bar
// vmcnt never drains to 0 mid-loop (tile t+1 loads stay in flight).
// ------------------------------------------------------------------
template<bool DIV>
__global__ __launch_bounds__(512, 1) void fused_kernel(
    const unsigned short* __restrict__ CKQ,   // [2048][2048]: K cols 0:1024, Q cols 1024:2048 (raw)
    const unsigned short* __restrict__ AUXT,  // TKQ (F1: K^T) or QsT (F2): rows h*64+z
    unsigned short* __restrict__ C,           // CB12 [2048][2048]
    float* __restrict__ Lg)                   // [16][2048] (F1 only)
{
  __shared__ __align__(16) char pool[114688];
  float* Red   = (float*)pool;                 // [2][64][132] f32, post-loop
  float* L_lds = (float*)(pool + 98304);       // post-loop (PB region)
  unsigned short* PB = (unsigned short*)(pool + 98304);

  int tid = threadIdx.x, lane = tid & 63, wave = tid >> 6;
  int iw = wave >> 1, pw = wave & 1;           // inner quarter / persist-64 half
  int zr = lane & 31, hi = lane >> 5;
  // bijective XCD swizzle (nwg=256 divisible by 8)
  int lin = blockIdx.x;
  int wgid = (lin & 7) * 32 + (lin >> 3);
  int h = wgid >> 4, p0 = (wgid & 15) << 7;    // head, persist base (128 rows)
  int h64 = h * 64;
  int cA = DIV ? h64 : TD + h64;            // inner-tile cols (F1: K, F2: Q)
  int cB = DIV ? TD + h64 : h64;            // persistent cols (F1: Q, F2: K)
  const unsigned short* AuxG = AUXT + (size_t)h64 * 2048;

  auto stageAin = [&](char* dst, int i0) {   // 128 inner x 64 z
    #pragma unroll
    for (int i = 0; i < 2; i++) {
      int c = i * 512 + tid, row = c >> 3, scol = ((c & 7) ^ (row & 7)) << 3;
      __builtin_amdgcn_global_load_lds((glb_u32*)(CKQ + (size_t)(i0 + row) * 2048 + cA + scol),
          (lds_u32*)(dst + i * 8192 + wave * 1024), 16, 0, 0);
    }
  };
  auto stageAux = [&](char* dst, int i0) {   // 64 z x 128 inner
    #pragma unroll
    for (int i = 0; i < 2; i++) {
      int c = i * 512 + tid, row = c >> 4, scol = ((c & 15) ^ (row & 15)) << 3;
      __builtin_amdgcn_global_load_lds((glb_u32*)(AuxG + (size_t)row * 2048 + i0 + scol),
          (lds_u32*)(dst + i * 8192 + wave * 1024), 16, 0, 0);
    }
  };

  // prologue: stage PB (128 persist x 64 z) + tiles 0,1
  #pragma unroll
  for (int i = 0; i < 2; i++) {
    int c = i * 512 + tid, row = c >> 3, scol = ((c & 7) ^ (row & 7)) << 3;
    __builtin_amdgcn_global_load_lds((glb_u32*)(CKQ + (size_t)(p0 + row) * 2048 + cB + scol),
        (lds_u32*)((char*)PB + i * 8192 + wave * 1024), 16, 0, 0);
  }
  stageAin(pool, 0);                 stageAux(pool + 49152, 0);
  stageAin(pool + 16384, 128);       stageAux(pool + 49152 + 16384, 128);
  wait_vm_lgkm0<4>();                // PB + tile0 landed; tile1 in flight
  __builtin_amdgcn_s_barrier();

  // hoist persistent S B-fragments: 2 sets (ps), rows pw*64+ps*32+zr
  bf16x8 bs[2][4];
  #pragma unroll
  for (int ps = 0; ps < 2; ps++)
    #pragma unroll
    for (int kz = 0; kz < 4; kz++)
      bs[ps][kz] = ld8(PB, pw * 64 + ps * 32 + zr, 2 * kz + hi);

  // per-lane LDS byte offsets (identical to round 10)
  int aoff[4];                       // S A-frag: Ain row iw*32+zr, slot 2kz+hi
  #pragma unroll
  for (int kz = 0; kz < 4; kz++) {
    int row = iw * 32 + zr;
    aoff[kz] = row * 128 + (((2 * kz + hi) ^ (row & 7)) << 4);
  }
  int boff[2][2][2];                 // PV B-frag: Aux row zb*32+zr, slot 4iw+2ks+d, half hi
  #pragma unroll
  for (int zb = 0; zb < 2; zb++)
    #pragma unroll
    for (int ks = 0; ks < 2; ks++)
      #pragma unroll
      for (int d = 0; d < 2; d++) {
        int zrow = zb * 32 + zr;
        int l = 4 * iw + 2 * ks + d;
        boff[zb][ks][d] = zrow * 256 + ((l ^ (zrow & 15)) << 4) + hi * 8;
      }

  f32x16 acc_pv[2][2] = {};          // [ps][zb]
  float lsum[2] = {0.f, 0.f};
  int bc = 0;

  for (int t = 0; t < 16; t++) {
    int bp = bc + 2; if (bp >= 3) bp -= 3;
    const char* curA = pool + bc * 16384;
    const char* curX = pool + 49152 + bc * 16384;
    bool pf = (t + 2 < 16);

    // ======== P0: a-frags || stageAin ; S-MFMA cluster ========
    bf16x8 a_[4];
    #pragma unroll
    for (int kz = 0; kz < 4; kz++) a_[kz] = *(const bf16x8*)(curA + aoff[kz]);
    if (pf) stageAin(pool + bp * 16384, (t + 2) * 128);
    __builtin_amdgcn_s_barrier();
    lgkm0_fence();
    f32x16 acc_s[2] = {};
    __builtin_amdgcn_s_setprio(1);
    #pragma unroll
    for (int kz = 0; kz < 4; kz++) {
      acc_s[0] = __builtin_amdgcn_mfma_f32_32x32x16_bf16(a_[kz], bs[0][kz], acc_s[0], 0, 0, 0);
      acc_s[1] = __builtin_amdgcn_mfma_f32_32x32x16_bf16(a_[kz], bs[1][kz], acc_s[1], 0, 0, 0);
    }
    __builtin_amdgcn_s_setprio(0);
    __builtin_amdgcn_s_barrier();

    // ======== P1: pb(zb0) || stageAux ; exp2+cvt ; PV zb0 ========
    uint2 pb0[2][2];
    #pragma unroll
    for (int ks = 0; ks < 2; ks++)
      #pragma unroll
      for (int d = 0; d < 2; d++)
        pb0[ks][d] = *(const uint2*)(curX + boff[0][ks][d]);
    if (pf) stageAux(pool + 49152 + bp * 16384, (t + 2) * 128);
    // exp2(SCL*acc) + pack (register-dependent on S-MFMA; overlaps other waves)
    union { bf16x8 v; uint32_t w[4]; } pu[2][2];
    #pragma unroll
    for (int ps = 0; ps < 2; ps++) {
      float ev[16];
      #pragma unroll
      for (int r = 0; r < 16; r++) ev[r] = exp2f(acc_s[ps][r] * SCL);
      if (DIV) {
        #pragma unroll
        for (int r = 0; r < 16; r++) lsum[ps] += ev[r];
      }
      #pragma unroll
      for (int ks = 0; ks < 2; ks++)
        #pragma unroll
        for (int i = 0; i < 4; i++)
          asm("v_cvt_pk_bf16_f32 %0, %1, %2"
              : "=v"(pu[ps][ks].w[i]) : "v"(ev[8 * ks + 2 * i]), "v"(ev[8 * ks + 2 * i + 1]));
    }
    __builtin_amdgcn_s_barrier();
    lgkm0_fence();
    __builtin_amdgcn_s_setprio(1);
    #pragma unroll
    for (int ks = 0; ks < 2; ks++) {
      union { bf16x8 v; uint2 u[2]; } bb;
      bb.u[0] = pb0[ks][0];
      bb.u[1] = pb0[ks][1];
      acc_pv[0][0] = __builtin_amdgcn_mfma_f32_32x32x16_bf16(pu[0][ks].v, bb.v, acc_pv[0][0], 0, 0, 0);
      acc_pv[1][0] = __builtin_amdgcn_mfma_f32_32x32x16_bf16(pu[1][ks].v, bb.v, acc_pv[1][0], 0, 0, 0);
    }
    __builtin_amdgcn_s_setprio(0);
    __builtin_amdgcn_s_barrier();

    // ======== P2: pb(zb1) ; PV zb1 ; counted vmcnt ========
    uint2 pb1[2][2];
    #pragma unroll
    for (int ks = 0; ks < 2; ks++)
      #pragma unroll
      for (int d = 0; d < 2; d++)
        pb1[ks][d] = *(const uint2*)(curX + boff[1][ks][d]);
    __builtin_amdgcn_s_barrier();
    lgkm0_fence();
    __builtin_amdgcn_s_setprio(1);
    #pragma unroll
    for (int ks = 0; ks < 2; ks++) {
      union { bf16x8 v; uint2 u[2]; } bb;
      bb.u[0] = pb1[ks][0];
      bb.u[1] = pb1[ks][1];
      acc_pv[0][1] = __builtin_amdgcn_mfma_f32_32x32x16_bf16(pu[0][ks].v, bb.v, acc_pv[0][1], 0, 0, 0);
      acc_pv[1][1] = __builtin_amdgcn_mfma_f32_32x32x16_bf16(pu[1][ks].v, bb.v, acc_pv[1][1], 0, 0, 0);
    }
    __builtin_amdgcn_s_setprio(0);
    if (pf) wait_vm_lgkm0<4>(); else wait_vm_lgkm0<0>();
    __builtin_amdgcn_s_barrier();
    bc = (bc == 2) ? 0 : bc + 1;
  }

  // ---- cross-iw reduction, two-phase f32 overlay (identical to round 10)
  if (iw >= 2) {
    #pragma unroll
    for (int ps = 0; ps < 2; ps++)
      #pragma unroll
      for (int zb = 0; zb < 2; zb++) {
        int z = zb * 32 + zr;
        #pragma unroll
        for (int u = 0; u < 4; u++) {
          int p = pw * 64 + ps * 32 + 8 * u + 4 * hi;
          f32x4 q;
          q[0] = acc_pv[ps][zb][4 * u];     q[1] = acc_pv[ps][zb][4 * u + 1];
          q[2] = acc_pv[ps][zb][4 * u + 2]; q[3] = acc_pv[ps][zb][4 * u + 3];
          *(f32x4*)&Red[(size_t)((iw - 2) * 64 + z) * 132 + p] = q;
        }
      }
  }
  if (DIV && tid < 128) L_lds[tid] = 0.f;
  __syncthreads();
  if (iw < 2) {
    #pragma unroll
    for (int ps = 0; ps < 2; ps++)
      #pragma unroll
      for (int zb = 0; zb < 2; zb++) {
        int z = zb * 32 + zr;
        #pragma unroll
        for (int u = 0; u < 4; u++) {
          int p = pw * 64 + ps * 32 + 8 * u + 4 * hi;
          float* slot = &Red[(size_t)(iw * 64 + z) * 132 + p];
          f32x4 q = *(f32x4*)slot;
          q[0] += acc_pv[ps][zb][4 * u];     q[1] += acc_pv[ps][zb][4 * u + 1];
          q[2] += acc_pv[ps][zb][4 * u + 2]; q[3] += acc_pv[ps][zb][4 * u + 3];
          *(f32x4*)slot = q;
        }
      }
  }
  if (DIV) {
    #pragma unroll
    for (int ps = 0; ps < 2; ps++) {
      float s = lsum[ps];
      s += __shfl_xor(s, 32);                // combine hi halves (same persist col)
      if (hi == 0) atomicAdd(&L_lds[pw * 64 + ps * 32 + zr], s);
    }
  }
  __syncthreads();
  if (DIV && tid < 128) Lg[(size_t)h * NT + p0 + tid] = L_lds[tid];
  int p = tid >> 2, z16 = (tid & 3) * 16;
  float inv = DIV ? 1.0f / L_lds[p] : 1.0f;
  int cbase = DIV ? h64 : TD + h64;
  unsigned short ob[16];
  #pragma unroll
  for (int i = 0; i < 16; i++) {
    int z = z16 + i;
    float x = Red[(size_t)z * 132 + p] + Red[(size_t)(64 + z) * 132 + p];
    ob[i] = f2bf(x * inv);
  }
  unsigned short* dst = C + (size_t)(p0 + p) * 2048 + cbase + z16;
  *(ushort4*)dst        = *(ushort4*)&ob[0];
  *(ushort4*)(dst + 4)  = *(ushort4*)&ob[4];
  *(ushort4*)(dst + 8)  = *(ushort4*)&ob[8];
  *(ushort4*)(dst + 12) = *(ushort4*)&ob[12];
}

// ------------------------------------------------------------------
extern "C" void kernel_launch(void* const* d_in, const int* in_sizes, int n_in,
                              void* d_out, int out_size, void* d_ws, size_t ws_size,
                              hipStream_t stream)
{
  (void)in_sizes; (void)n_in; (void)out_size; (void)ws_size;
  const float* g  = (const float*)d_in[0];
  const float* Wk = (const float*)d_in[1];
  const float* Wq = (const float*)d_in[2];

  char* ws = (char*)d_ws;
  size_t off = 0;
  auto alloc = [&](size_t b) -> char* {
    char* p = ws + off; off += (b + 255) & ~((size_t)255); return p;
  };
  unsigned short* gbf  = (unsigned short*)alloc((size_t)NT * TD * 2);     // 4 MB
  unsigned short* wkq  = (unsigned short*)alloc((size_t)2 * TD * TD * 2); // 4 MB
  unsigned short* twqk = (unsigned short*)alloc((size_t)TD * 2048 * 2);   // 4 MB
  unsigned short* CKQ  = (unsigned short*)alloc((size_t)NT * 2048 * 2);   // 8 MB
  unsigned short* TKQ  = (unsigned short*)alloc((size_t)NT * 2048 * 2);   // 8 MB
  unsigned short* CB12 = (unsigned short*)alloc((size_t)NT * 2048 * 2);   // 8 MB
  unsigned short* QsT  = (unsigned short*)alloc((size_t)TD * NT * 2);     // 4 MB
  float*          Lbuf = (float*)alloc((size_t)NH * NT * 4);              // 128 KB

  prep_kernel<<<dim3(4096), dim3(256), 0, stream>>>(g, Wk, Wq, gbf, wkq, twqk);

  // K,Q = g * [Wk;Wq]^T -> CKQ [tok][2048] (raw)
  btg2_kernel<128, 64, 0, 2><<<dim3(16, 32), dim3(256), 0, stream>>>(
      gbf, TD, wkq, TD, TD, (void*)CKQ);

  // TKQ = CKQ^T (coalesced transpose)
  transp_kernel<<<dim3(4096), dim3(256), 0, stream>>>(CKQ, TKQ);

  // F1: B1 (normalized) -> CB12 cols [h*64, h*64+64), plus L
  fused_kernel<true><<<dim3(256), dim3(512), 0, stream>>>(CKQ, TKQ, CB12, Lbuf);

  // Qn^T = Q^T / L
  qst_kernel<<<dim3(1024), dim3(256), 0, stream>>>(TKQ, Lbuf, QsT);

  // F2: B2 -> CB12 cols [1024+h*64, ...)
  fused_kernel<false><<<dim3(256), dim3(512), 0, stream>>>(CKQ, QsT, CB12, nullptr);

  // out = -( CB12 * twqk^T )   (f32)
  btg2_kernel<64, 64, 4, 3><<<dim3(32, 16), dim3(256), 0, stream>>>(
      CB12, 2048, twqk, 2048, 2048, d_out);
}

// Round 12
// 111.816 us; speedup vs baseline: 1.1481x; 1.1481x over previous
//
#include <hip/hip_runtime.h>
#include <stdint.h>

#define NT 2048     // tokens
#define TD 1024     // token dim
#define NH 16       // heads
static constexpr float SCL = 0.18033688011112042f;  // beta*log2(e), applied in exp2

typedef __attribute__((ext_vector_type(8))) short bf16x8;
typedef __attribute__((ext_vector_type(4))) float f32x4;
typedef __attribute__((ext_vector_type(16))) float f32x16;
typedef __attribute__((address_space(3))) uint32_t lds_u32;
typedef __attribute__((address_space(1))) uint32_t glb_u32;

__device__ __forceinline__ float bf2f(unsigned short u){
  union { uint32_t u32; float f; } v; v.u32 = ((uint32_t)u) << 16; return v.f;
}
__device__ __forceinline__ unsigned short f2bf(float f){
  union { float f; uint32_t u; } v; v.f = f;
  uint32_t r = v.u + 0x7fffu + ((v.u >> 16) & 1u);   // RNE
  return (unsigned short)(r >> 16);
}
// 128B-row tile (8x16B slots), phys slot = kc ^ (row&7)  (btg2 staging)
__device__ __forceinline__ bf16x8 ld8(const unsigned short* base, int row, int kc){
  return *(const bf16x8*)((const char*)base + row*128 + ((kc ^ (row & 7)) << 4));
}
template<int N> __device__ __forceinline__ void wait_vm_lgkm0(){
  if constexpr (N == 0)      asm volatile("s_waitcnt vmcnt(0) lgkmcnt(0)" ::: "memory");
  else if constexpr (N == 4) asm volatile("s_waitcnt vmcnt(4) lgkmcnt(0)" ::: "memory");
  else if constexpr (N == 6) asm volatile("s_waitcnt vmcnt(6) lgkmcnt(0)" ::: "memory");
  __builtin_amdgcn_sched_barrier(0);
}

// ------------------------------------------------------------------
// prep: gbf = bf16(g); wkq = bf16([Wk;Wq]) rows hz2 x 1024;
//       twqk[d][j] = j<1024 ? Wq[j][d] : Wk[j-1024][d]  (bf16, 1024x2048)
// ------------------------------------------------------------------
__global__ __launch_bounds__(256) void prep_kernel(
    const float* __restrict__ g, const float* __restrict__ Wk, const float* __restrict__ Wq,
    unsigned short* __restrict__ gbf, unsigned short* __restrict__ wkq,
    unsigned short* __restrict__ twqk)
{
  int b = blockIdx.x;
  if (b < 1024) {
    int base = b * 2048 + threadIdx.x;
    #pragma unroll
    for (int i = 0; i < 8; i++) { int idx = base + i * 256; gbf[idx] = f2bf(g[idx]); }
  } else if (b < 2048) {
    int base = (b - 1024) * 2048 + threadIdx.x;
    #pragma unroll
    for (int i = 0; i < 8; i++) {
      int idx = base + i * 256;
      float v = (idx < (1 << 20)) ? Wk[idx] : Wq[idx - (1 << 20)];
      wkq[idx] = f2bf(v);
    }
  } else {
    int t = b - 2048;                  // 32 d-tiles x 64 j-tiles
    int dt = t & 31, jt = t >> 5;
    __shared__ float tile[32][33];
    int tx = threadIdx.x & 31, ty = threadIdx.x >> 5;
    int j0 = jt * 32, d0 = dt * 32;
    const float* src = (j0 < 1024) ? Wq : Wk;
    int jb = (j0 < 1024) ? j0 : (j0 - 1024);
    #pragma unroll
    for (int rr = 0; rr < 4; rr++)
      tile[ty + rr * 8][tx] = src[(size_t)(jb + ty + rr * 8) * 1024 + d0 + tx];
    __syncthreads();
    #pragma unroll
    for (int rr = 0; rr < 4; rr++)
      twqk[(size_t)(d0 + ty + rr * 8) * 2048 + j0 + tx] = f2bf(tile[tx][ty + rr * 8]);
  }
}

// ------------------------------------------------------------------
// pack_pck: PCK fragment layout for S-operands (A and B share the map).
//   fragment (cb in [0,32), rb in [0,64), kz in [0,4)): lane l, elem e:
//     tok = rb*32 + (l&31);  z = kz*16 + 8*(l>>5) + e;  col = cb*64 + z
//   flat bf16x8 index: ((cb*64+rb)*4 + kz)*64 + l
// ------------------------------------------------------------------
__global__ __launch_bounds__(256) void pack_pck(const unsigned short* __restrict__ CKQ,
                                                unsigned short* __restrict__ PCK)
{
  int tile = blockIdx.x;             // 2048 = 32 cb x 64 rb
  int cb = tile >> 6, rb = tile & 63;
  __shared__ unsigned short t[32][72];   // 32 tok x 64 z (stride 144B, 8B-aligned)
  int tid = threadIdx.x;
  int r = tid >> 3, c0 = (tid & 7) * 8;
  const unsigned short* src = CKQ + (size_t)(rb * 32 + r) * 2048 + cb * 64 + c0;
  *(ushort4*)&t[r][c0]     = *(const ushort4*)src;
  *(ushort4*)&t[r][c0 + 4] = *(const ushort4*)(src + 4);
  __syncthreads();
  int kz = tid >> 6, l = tid & 63;
  int zl = kz * 16 + 8 * (l >> 5);
  ushort4 lo = *(ushort4*)&t[l & 31][zl];
  ushort4 hi4 = *(ushort4*)&t[l & 31][zl + 4];
  unsigned short* dst = PCK + ((size_t)(tile * 4 + kz) * 64 + l) * 8;
  *(ushort4*)dst       = lo;
  *(ushort4*)(dst + 4) = hi4;
}

// ------------------------------------------------------------------
// pack_pbx: PBT (DIVL=false: K^T) / QSTP (DIVL=true: Q^T / L) PV-B fragments.
//   fragment ((h,zb), qb in [0,64), ks in [0,2)): lane l, elem e:
//     z-row = h*64 + zb*32 + (l&31)
//     q     = qb*32 + 16*ks + 8*(e>>2) + 4*(l>>5) + (e&3)     [sigma baked in]
//     value = CKQ[q][colbase + (l&31)]  (/ L[h][q] for QSTP)
//   flat bf16x8 index: (bid*2 + ks)*64 + l,  bid = (h*2+zb)*64 + qb
// ------------------------------------------------------------------
template<bool DIVL>
__global__ __launch_bounds__(256) void pack_pbx(const unsigned short* __restrict__ CKQ,
                                                const float* __restrict__ L,
                                                unsigned short* __restrict__ PBX)
{
  int bid = blockIdx.x;              // 2048 = (16h x 2zb) x 64 qb
  int qb = bid & 63, hz = bid >> 6;  // hz = h*2+zb
  int h = hz >> 1, zb = hz & 1;
  int colbase = (DIVL ? 1024 : 0) + h * 64 + zb * 32;
  __shared__ unsigned short tq[32][36];   // [q-local][z-local]
  __shared__ float rcpL[32];
  int tid = threadIdx.x;
  int r = tid >> 3, c0 = (tid & 7) * 4;
  *(ushort4*)&tq[r][c0] =
      *(const ushort4*)(CKQ + (size_t)(qb * 32 + r) * 2048 + colbase + c0);
  if (DIVL && tid < 32) rcpL[tid] = 1.0f / L[(size_t)h * NT + qb * 32 + tid];
  __syncthreads();
  if (tid < 128) {
    int ks = tid >> 6, l = tid & 63;
    int zl = l & 31, hi = l >> 5;
    unsigned short ob[8];
    #pragma unroll
    for (int e = 0; e < 8; e++) {
      int ql = 16 * ks + 8 * (e >> 2) + 4 * hi + (e & 3);
      unsigned short v = tq[ql][zl];
      if (DIVL) v = f2bf(bf2f(v) * rcpL[ql]);
      ob[e] = v;
    }
    unsigned short* dst = PBX + ((size_t)(bid * 2 + ks) * 64 + l) * 8;
    *(ushort4*)dst       = *(ushort4*)&ob[0];
    *(ushort4*)(dst + 4) = *(ushort4*)&ob[4];
  }
}

// ------------------------------------------------------------------
// btg2: C = A[M x K] * BT[N x K]^T, bf16, BK=64, triple-buffered counted vmcnt.
// EPI 0: C0 = bf16 C (ld 2048), coalesced rows only                  [KQ]
// EPI 4: C0 f32 [r][1024] = -acc                                     [out]
// ------------------------------------------------------------------
template<int TM, int TN, int EPI, int WPE>
__global__ __launch_bounds__(256, WPE) void btg2_kernel(
    const unsigned short* __restrict__ A, int lda,
    const unsigned short* __restrict__ BT, int ldb,
    int Kdim, void* C0)
{
  constexpr int WM = TM / 2, WN = TN / 2, FM = WM / 16, FN = WN / 16;
  constexpr int AC = TM / 32, BC = TN / 32, LOADS = AC + BC;
  __shared__ __align__(16) unsigned short As[3][TM * 64];
  __shared__ __align__(16) unsigned short Bs[3][TN * 64];
  int tid = threadIdx.x, lane = tid & 63, wave = tid >> 6;
  int wr = wave >> 1, wc = wave & 1, lrow = lane & 15, g = lane >> 4;
  int bm = blockIdx.x * TM, bn = blockIdx.y * TN;

  auto stage = [&](unsigned short* bufA, unsigned short* bufB, int kk) {
    #pragma unroll
    for (int i = 0; i < AC; i++) {
      int c = i * 256 + tid, row = c >> 3, sl = ((c & 7) ^ (row & 7)) << 3;
      __builtin_amdgcn_global_load_lds((glb_u32*)(A + (size_t)(bm + row) * lda + kk + sl),
          (lds_u32*)((char*)bufA + i * 4096 + wave * 1024), 16, 0, 0);
    }
    #pragma unroll
    for (int i = 0; i < BC; i++) {
      int c = i * 256 + tid, row = c >> 3, sl = ((c & 7) ^ (row & 7)) << 3;
      __builtin_amdgcn_global_load_lds((glb_u32*)(BT + (size_t)(bn + row) * ldb + kk + sl),
          (lds_u32*)((char*)bufB + i * 4096 + wave * 1024), 16, 0, 0);
    }
  };

  f32x4 acc[FM][FN] = {};
  int nt = Kdim >> 6;
  stage(As[0], Bs[0], 0);
  stage(As[1], Bs[1], 64);
  wait_vm_lgkm0<LOADS>();          // tile0 landed; tile1 still in flight
  __builtin_amdgcn_s_barrier();
  int bc = 0;
  for (int t = 0; t < nt; t++) {
    int bp = bc + 2; if (bp >= 3) bp -= 3;
    if (t + 2 < nt) stage(As[bp], Bs[bp], (t + 2) * 64);
    const unsigned short* Ac = As[bc];
    const unsigned short* Bc = Bs[bc];
    #pragma unroll
    for (int k2 = 0; k2 < 2; k2++) {
      bf16x8 a_[FM], b_[FN];
      #pragma unroll
      for (int m = 0; m < FM; m++) a_[m] = ld8(Ac, wr * WM + m * 16 + lrow, k2 * 4 + g);
      #pragma unroll
      for (int n = 0; n < FN; n++) b_[n] = ld8(Bc, wc * WN + n * 16 + lrow, k2 * 4 + g);
      #pragma unroll
      for (int m = 0; m < FM; m++)
        #pragma unroll
        for (int n = 0; n < FN; n++)
          acc[m][n] = __builtin_amdgcn_mfma_f32_16x16x32_bf16(a_[m], b_[n], acc[m][n], 0, 0, 0);
    }
    if (t + 2 < nt) wait_vm_lgkm0<LOADS>(); else wait_vm_lgkm0<0>();
    __builtin_amdgcn_s_barrier();
    bc = (bc == 2) ? 0 : bc + 1;
  }
  #pragma unroll
  for (int m = 0; m < FM; m++) {
    int rb = bm + wr * WM + m * 16 + 4 * g;
    #pragma unroll
    for (int n = 0; n < FN; n++) {
      int cc = bn + wc * WN + n * 16 + lrow;
      f32x4 v = acc[m][n];
      if constexpr (EPI == 0) {
        unsigned short* Cp = (unsigned short*)C0;
        #pragma unroll
        for (int j = 0; j < 4; j++) Cp[(size_t)(rb + j) * 2048 + cc] = f2bf(v[j]);
      } else {
        float* Cf = (float*)C0;
        #pragma unroll
        for (int j = 0; j < 4; j++) Cf[(size_t)(rb + j) * 1024 + cc] = -v[j];
      }
    }
  }
}

// ------------------------------------------------------------------
// fused v12: zero-barrier, zero-LDS main loop with COALESCED packed loads.
// Each wave autonomous: (head, persist-64, inner-512); per iter:
//   4 a-loads + 4 pb-loads (all global_load_dwordx4, base+lane*16, coalesced)
//   8 S-MFMA (a shared across 2 ps) -> 32 exp2 -> 16 cvt_pk -> 8 PV-MFMA
// 1-deep manual pipeline. Fragment bytes identical to verified round-10 reads
// (sigma baked into PBT/QSTP). End: round-10 two-phase Red reduction.
// ------------------------------------------------------------------
template<bool DIV>
__global__ __launch_bounds__(256, 2) void fused_kernel(
    const unsigned short* __restrict__ PCK,   // packed CKQ fragments
    const unsigned short* __restrict__ PBX,   // PBT (F1) or QSTP (F2)
    unsigned short* __restrict__ C,           // CB12 [2048][2048]
    float* __restrict__ Lg)                   // [16][2048] (F1 only)
{
  __shared__ __align__(16) float Red[2][64][68];   // ~34.8 KB
  __shared__ float L_lds[64];
  int tid = threadIdx.x, l = tid & 63, w = tid >> 6;
  int zr = l & 31, hi = l >> 5;
  int lin = blockIdx.x;                      // 512 blocks, bijective XCD swizzle
  int wgid = (lin & 7) * 64 + (lin >> 3);
  int h = wgid >> 5, pB = wgid & 31, p0 = pB * 64;
  int cbA = DIV ? h : 16 + h;                // inner cols (F1: K, F2: Q)
  int cbB = DIV ? 16 + h : h;                // persist cols (F1: Q, F2: K)
  const bf16x8* PCKf = (const bf16x8*)PCK;
  const bf16x8* PBXf = (const bf16x8*)PBX;

  // persistent S B-fragments (2 x 32-persist sets)
  bf16x8 bs[2][4];
  #pragma unroll
  for (int ps = 0; ps < 2; ps++)
    #pragma unroll
    for (int kz = 0; kz < 4; kz++)
      bs[ps][kz] = PCKf[((size_t)(cbB * 64 + pB * 2 + ps) * 4 + kz) * 64 + l];

  auto load = [&](bf16x8 (&a_)[4], bf16x8 (&pb_)[2][2], int rb){
    #pragma unroll
    for (int kz = 0; kz < 4; kz++)
      a_[kz] = PCKf[((size_t)(cbA * 64 + rb) * 4 + kz) * 64 + l];
    #pragma unroll
    for (int zb = 0; zb < 2; zb++)
      #pragma unroll
      for (int ks = 0; ks < 2; ks++)
        pb_[zb][ks] = PBXf[((size_t)((h * 2 + zb) * 64 + rb) * 2 + ks) * 64 + l];
  };

  f32x16 acc_pv[2][2] = {};                  // [ps][zb]
  float lsum[2] = {0.f, 0.f};
  bf16x8 a_c[4], pb_c[2][2];
  load(a_c, pb_c, w * 16);

  for (int t = 0; t < 16; t++) {
    bf16x8 a_n[4], pb_n[2][2];
    if (t + 1 < 16) load(a_n, pb_n, w * 16 + t + 1);
    // ---- S: inner-32 x persist-64, contract z=64
    f32x16 acc_s[2] = {};
    #pragma unroll
    for (int kz = 0; kz < 4; kz++) {
      acc_s[0] = __builtin_amdgcn_mfma_f32_32x32x16_bf16(a_c[kz], bs[0][kz], acc_s[0], 0, 0, 0);
      acc_s[1] = __builtin_amdgcn_mfma_f32_32x32x16_bf16(a_c[kz], bs[1][kz], acc_s[1], 0, 0, 0);
    }
    // ---- exp2(SCL*acc); acc halves are the PV A-fragments (verified sigma)
    union { bf16x8 v; uint32_t u[4]; } pu[2][2];
    #pragma unroll
    for (int ps = 0; ps < 2; ps++) {
      float ev[16];
      #pragma unroll
      for (int r = 0; r < 16; r++) ev[r] = exp2f(acc_s[ps][r] * SCL);
      if (DIV) {
        #pragma unroll
        for (int r = 0; r < 16; r++) lsum[ps] += ev[r];
      }
      #pragma unroll
      for (int ks = 0; ks < 2; ks++)
        #pragma unroll
        for (int i = 0; i < 4; i++)
          asm("v_cvt_pk_bf16_f32 %0, %1, %2"
              : "=v"(pu[ps][ks].u[i]) : "v"(ev[8 * ks + 2 * i]), "v"(ev[8 * ks + 2 * i + 1]));
    }
    // ---- PV: persist-64 x z-64, contract this tile's inner-32
    #pragma unroll
    for (int zb = 0; zb < 2; zb++)
      #pragma unroll
      for (int ks = 0; ks < 2; ks++) {
        acc_pv[0][zb] = __builtin_amdgcn_mfma_f32_32x32x16_bf16(pu[0][ks].v, pb_c[zb][ks], acc_pv[0][zb], 0, 0, 0);
        acc_pv[1][zb] = __builtin_amdgcn_mfma_f32_32x32x16_bf16(pu[1][ks].v, pb_c[zb][ks], acc_pv[1][zb], 0, 0, 0);
      }
    #pragma unroll
    for (int kz = 0; kz < 4; kz++) a_c[kz] = a_n[kz];
    #pragma unroll
    for (int zb = 0; zb < 2; zb++)
      #pragma unroll
      for (int ks = 0; ks < 2; ks++) pb_c[zb][ks] = pb_n[zb][ks];
  }

  // ---- cross-wave (4 inner-quarter) two-phase reduction (round-10 verified)
  if (w >= 2) {
    #pragma unroll
    for (int ps = 0; ps < 2; ps++)
      #pragma unroll
      for (int zb = 0; zb < 2; zb++) {
        int z = zb * 32 + zr;
        #pragma unroll
        for (int u = 0; u < 4; u++) {
          int p = ps * 32 + 8 * u + 4 * hi;
          f32x4 q;
          q[0] = acc_pv[ps][zb][4 * u];     q[1] = acc_pv[ps][zb][4 * u + 1];
          q[2] = acc_pv[ps][zb][4 * u + 2]; q[3] = acc_pv[ps][zb][4 * u + 3];
          *(f32x4*)&Red[w - 2][z][p] = q;
        }
      }
  }
  if (DIV && tid < 64) L_lds[tid] = 0.f;
  __syncthreads();
  if (w < 2) {
    #pragma unroll
    for (int ps = 0; ps < 2; ps++)
      #pragma unroll
      for (int zb = 0; zb < 2; zb++) {
        int z = zb * 32 + zr;
        #pragma unroll
        for (int u = 0; u < 4; u++) {
          int p = ps * 32 + 8 * u + 4 * hi;
          float* slot = &Red[w][z][p];
          f32x4 q = *(f32x4*)slot;
          q[0] += acc_pv[ps][zb][4 * u];     q[1] += acc_pv[ps][zb][4 * u + 1];
          q[2] += acc_pv[ps][zb][4 * u + 2]; q[3] += acc_pv[ps][zb][4 * u + 3];
          *(f32x4*)slot = q;
        }
      }
  }
  if (DIV) {
    #pragma unroll
    for (int ps = 0; ps < 2; ps++) {
      float s = lsum[ps];
      s += __shfl_xor(s, 32);                // combine hi halves (same persist col)
      if (hi == 0) atomicAdd(&L_lds[ps * 32 + zr], s);
    }
  }
  __syncthreads();
  if (DIV && tid < 64) Lg[(size_t)h * NT + p0 + tid] = L_lds[tid];
  // output: thread -> p = tid>>2 (0..63), z-range (tid&3)*16
  int p = tid >> 2, z16 = (tid & 3) * 16;
  float inv = DIV ? 1.0f / L_lds[p] : 1.0f;
  int cbase = DIV ? h * 64 : TD + h * 64;
  unsigned short ob[16];
  #pragma unroll
  for (int i = 0; i < 16; i++) {
    int z = z16 + i;
    float x = Red[0][z][p] + Red[1][z][p];
    ob[i] = f2bf(x * inv);
  }
  unsigned short* dst = C + (size_t)(p0 + p) * 2048 + cbase + z16;
  *(ushort4*)dst        = *(ushort4*)&ob[0];
  *(ushort4*)(dst + 4)  = *(ushort4*)&ob[4];
  *(ushort4*)(dst + 8)  = *(ushort4*)&ob[8];
  *(ushort4*)(dst + 12) = *(ushort4*)&ob[12];
}

// ------------------------------------------------------------------
extern "C" void kernel_launch(void* const* d_in, const int* in_sizes, int n_in,
                              void* d_out, int out_size, void* d_ws, size_t ws_size,
                              hipStream_t stream)
{
  (void)in_sizes; (void)n_in; (void)out_size; (void)ws_size;
  const float* g  = (const float*)d_in[0];
  const float* Wk = (const float*)d_in[1];
  const float* Wq = (const float*)d_in[2];

  char* ws = (char*)d_ws;
  size_t off = 0;
  auto alloc = [&](size_t b) -> char* {
    char* p = ws + off; off += (b + 255) & ~((size_t)255); return p;
  };
  unsigned short* gbf  = (unsigned short*)alloc((size_t)NT * TD * 2);     // 4 MB
  unsigned short* wkq  = (unsigned short*)alloc((size_t)2 * TD * TD * 2); // 4 MB
  unsigned short* twqk = (unsigned short*)alloc((size_t)TD * 2048 * 2);   // 4 MB
  unsigned short* CKQ  = (unsigned short*)alloc((size_t)NT * 2048 * 2);   // 8 MB
  unsigned short* PCK  = (unsigned short*)alloc((size_t)NT * 2048 * 2);   // 8 MB
  unsigned short* PBT  = (unsigned short*)alloc((size_t)TD * NT * 2);     // 4 MB
  unsigned short* QSTP = (unsigned short*)alloc((size_t)TD * NT * 2);     // 4 MB
  unsigned short* CB12 = (unsigned short*)alloc((size_t)NT * 2048 * 2);   // 8 MB
  float*          Lbuf = (float*)alloc((size_t)NH * NT * 4);              // 128 KB

  prep_kernel<<<dim3(4096), dim3(256), 0, stream>>>(g, Wk, Wq, gbf, wkq, twqk);

  // K,Q = g * [Wk;Wq]^T -> CKQ [tok][2048] (row-major)
  btg2_kernel<128, 64, 0, 2><<<dim3(16, 32), dim3(256), 0, stream>>>(
      gbf, TD, wkq, TD, TD, (void*)CKQ);

  // packed operand layouts
  pack_pck<<<dim3(2048), dim3(256), 0, stream>>>(CKQ, PCK);
  pack_pbx<false><<<dim3(2048), dim3(256), 0, stream>>>(CKQ, nullptr, PBT);

  // F1: B1 (normalized) -> CB12 cols [h*64, h*64+64), plus L
  fused_kernel<true><<<dim3(512), dim3(256), 0, stream>>>(PCK, PBT, CB12, Lbuf);

  // QSTP = packed Q^T / L
  pack_pbx<true><<<dim3(2048), dim3(256), 0, stream>>>(CKQ, Lbuf, QSTP);

  // F2: B2 -> CB12 cols [1024+h*64, ...)
  fused_kernel<false><<<dim3(512), dim3(256), 0, stream>>>(PCK, QSTP, CB12, nullptr);

  // out = -( CB12 * twqk^T )   (f32)
  btg2_kernel<64, 64, 4, 3><<<dim3(32, 16), dim3(256), 0, stream>>>(
      CB12, 2048, twqk, 2048, 2048, d_out);
}